// Round 3
// baseline (308.456 us; speedup 1.0000x reference)
//
#include <hip/hip_runtime.h>

// XOR-conv as implicit-GEMM MFMA (bf16 inputs, fp32 accum).
// out[b,co,ho,wo] = sum_{ci,kh,kw} x[b,ci,ho+kh,wo+kw] * (1-2*W[co,ci,kh,kw])
// Shapes: B=32, CI=128, H=W=64, CO=256, K=3, HO=WO=62.
//
// R3: x pre-converted to bf16 in staging order [b][h][cc][c][ci32] so the main
// kernel's LDS staging is 6 coalesced uint4 loads + 6 ds_write_b128 per thread
// per chunk (single vmcnt wait), removing the per-iteration latency chain that
// kept all pipes <20% busy in R2. W stays A-frag-packed, read from L2.

typedef __bf16 bf16x8 __attribute__((ext_vector_type(8)));
typedef float  f32x4  __attribute__((ext_vector_type(4)));

#define CIPAD 40  // 32-ci chunk padded to 40 ushorts (80B col stride; uniform bank walk)

// ---- prepack W: fp32 [co][ci][3][3] in {0,1} -> bf16 bits in A-frag order ----
// layout: [e(9)][cc(4)][tile(16)][lane(64)][j(8)]
__global__ void prepack_w_kernel(const float* __restrict__ Wf,
                                 unsigned short* __restrict__ effw) {
  int idx = blockIdx.x * 256 + threadIdx.x;     // 294912
  if (idx >= 9 * 4 * 16 * 64 * 8) return;
  int j    = idx & 7;
  int lane = (idx >> 3) & 63;
  int tile = (idx >> 9) & 15;
  int cc   = (idx >> 13) & 3;
  int e    = idx >> 15;
  int co = tile * 16 + (lane & 15);
  int ci = cc * 32 + (lane >> 4) * 8 + j;
  float w = Wf[(co * 128 + ci) * 9 + e];
  __bf16 h = (__bf16)(1.0f - 2.0f * w);         // exactly +-1
  unsigned short u; __builtin_memcpy(&u, &h, 2);
  effw[idx] = u;
}

// ---- prepack x: fp32 NCHW -> bf16 [b(32)][h(64)][cc(4)][c(64)][ci(32)] ----
__global__ void prepack_x_kernel(const float* __restrict__ x,
                                 unsigned short* __restrict__ xbf) {
  int t = blockIdx.x * 256 + threadIdx.x;       // 32*64*4*4*64 = 2097152
  if (t >= 32 * 64 * 4 * 4 * 64) return;
  int c  = t & 63;
  int q  = (t >> 6) & 3;
  int cc = (t >> 8) & 3;
  int h  = (t >> 10) & 63;
  int b  = t >> 16;
  int ci0 = cc * 32 + q * 8;
  unsigned short u[8];
  #pragma unroll
  for (int j = 0; j < 8; ++j) {
    float f = x[((size_t)(b * 128 + ci0 + j) * 64 + h) * 64 + c];  // c-lanes coalesced
    __bf16 hh = (__bf16)f;
    __builtin_memcpy(&u[j], &hh, 2);
  }
  size_t idx = ((((size_t)(b * 64 + h) * 4 + cc) * 64 + c) * 32) + q * 8;
  *(uint4*)&xbf[idx] = *(const uint4*)u;
}

// ================= main kernel, prepacked-x path =================
// Block: 256 threads = 4 waves. Tile: 128 co x (4 output rows x 64 virtual cols).
__global__ __launch_bounds__(256, 2)
void xorconv_mfma_pre(const unsigned short* __restrict__ xbf,
                      const unsigned short* __restrict__ effw,
                      float* __restrict__ out) {
  __shared__ __align__(16) unsigned short xs[6 * 66 * CIPAD];  // 31.7KB

  const int tid    = threadIdx.x;
  const int bxc    = blockIdx.x;
  const int co_blk = bxc * 128;
  const int hbase  = blockIdx.y * 4;
  const int bb     = blockIdx.z;

  const int wv   = tid >> 6;
  const int lane = tid & 63;
  const int quad = lane >> 4;
  const int l16  = lane & 15;

  const int qst = tid & 3;            // staging: ci-quad
  const int cst = (tid >> 2) & 63;    // staging: column

  f32x4 acc[8][4];
  #pragma unroll
  for (int i = 0; i < 8; ++i)
    #pragma unroll
    for (int j = 0; j < 4; ++j)
      acc[i][j] = (f32x4){0.f, 0.f, 0.f, 0.f};

  for (int cc = 0; cc < 4; ++cc) {
    // ---- stage x: 6 coalesced 16B loads (one vmcnt wait), 6 ds_write_b128 ----
    uint4 v[6];
    #pragma unroll
    for (int r = 0; r < 6; ++r) {
      int h_in = hbase + r; if (h_in > 63) h_in = 63;   // feeds only masked ho>=62
      const unsigned short* sp =
          xbf + ((((size_t)(bb * 64 + h_in) * 4 + cc) * 64 + cst) * 32) + qst * 8;
      v[r] = *(const uint4*)sp;
    }
    #pragma unroll
    for (int r = 0; r < 6; ++r)
      *(uint4*)&xs[(r * 66 + cst) * CIPAD + qst * 8] = v[r];
    // cols 64,65 of xs left unwritten: garbage feeds only masked wo>=62
    __syncthreads();

    // ---- 9 taps, barrier-free: W A-frags straight from global (L1/L2-hot) ----
    for (int e = 0; e < 9; ++e) {
      const int kh = e / 3;
      const int kw = e - 3 * kh;
      const int rr = wv + kh;

      bf16x8 bfr[4];
      #pragma unroll
      for (int j = 0; j < 4; ++j) {
        int ccol = j * 16 + l16 + kw;
        bfr[j] = *(const bf16x8*)&xs[(rr * 66 + ccol) * CIPAD + quad * 8];
      }
      const unsigned short* wp =
          effw + ((((size_t)e * 4 + cc) * 16 + bxc * 8) * 64 + lane) * 8;
      #pragma unroll
      for (int mt = 0; mt < 8; ++mt) {
        bf16x8 af = *(const bf16x8*)(wp + (size_t)mt * 512);
        #pragma unroll
        for (int j = 0; j < 4; ++j)
          acc[mt][j] = __builtin_amdgcn_mfma_f32_16x16x32_bf16(af, bfr[j], acc[mt][j], 0, 0, 0);
      }
    }
    __syncthreads();
  }

  // ---- epilogue: C/D layout col(n)=lane&15, row(m)=quad*4+reg ----
  const int ho = hbase + wv;
  if (ho < 62) {
    #pragma unroll
    for (int mt = 0; mt < 8; ++mt) {
      const int co = co_blk + mt * 16 + quad * 4;
      #pragma unroll
      for (int j = 0; j < 4; ++j) {
        const int wo = j * 16 + l16;
        if (wo < 62) {
          float* op = out + (((size_t)(bb * 256 + co) * 62 + ho) * 62 + wo);
          #pragma unroll
          for (int rg = 0; rg < 4; ++rg)
            op[(size_t)rg * 3844] = acc[mt][j][rg];
        }
      }
    }
  }
}

// ================= fallback (R2 path) if ws too small for xbf =================
__global__ __launch_bounds__(256, 2)
void xorconv_mfma_fb(const float* __restrict__ x,
                     const unsigned short* __restrict__ effw,
                     float* __restrict__ out) {
  __shared__ __align__(16) unsigned short xs[6 * 66 * CIPAD];
  const int tid    = threadIdx.x;
  const int bxc    = blockIdx.x;
  const int co_blk = bxc * 128;
  const int hbase  = blockIdx.y * 4;
  const int bb     = blockIdx.z;
  const int wv   = tid >> 6;
  const int lane = tid & 63;
  const int quad = lane >> 4;
  const int l16  = lane & 15;

  f32x4 acc[8][4];
  #pragma unroll
  for (int i = 0; i < 8; ++i)
    #pragma unroll
    for (int j = 0; j < 4; ++j)
      acc[i][j] = (f32x4){0.f, 0.f, 0.f, 0.f};

  unsigned int* xs32 = (unsigned int*)xs;

  for (int cc = 0; cc < 4; ++cc) {
    const int c0 = cc * 32;
    for (int p2 = tid; p2 < 6 * 33 * 16; p2 += 256) {
      int c2  = p2 % 33;
      int t2  = p2 / 33;
      int ci2 = t2 & 15;
      int r   = t2 >> 4;
      int c   = c2 * 2;
      int h_in = hbase + r; if (h_in > 63) h_in = 63;
      int c_in = c;         if (c_in > 62) c_in = 62;
      const float* gp = x + (((size_t)(bb * 128 + c0 + ci2 * 2) * 64 + h_in) * 64 + c_in);
      float f00 = gp[0],    f01 = gp[1];
      float f10 = gp[4096], f11 = gp[4097];
      __bf16 h00 = (__bf16)f00, h01 = (__bf16)f01, h10 = (__bf16)f10, h11 = (__bf16)f11;
      unsigned short u00, u01, u10, u11;
      __builtin_memcpy(&u00, &h00, 2); __builtin_memcpy(&u01, &h01, 2);
      __builtin_memcpy(&u10, &h10, 2); __builtin_memcpy(&u11, &h11, 2);
      xs32[(r * 66 + c) * (CIPAD / 2) + ci2]     = (unsigned)u00 | ((unsigned)u10 << 16);
      xs32[(r * 66 + c + 1) * (CIPAD / 2) + ci2] = (unsigned)u01 | ((unsigned)u11 << 16);
    }
    __syncthreads();
    for (int e = 0; e < 9; ++e) {
      const int kh = e / 3;
      const int kw = e - 3 * kh;
      const int rr = wv + kh;
      bf16x8 bfr[4];
      #pragma unroll
      for (int j = 0; j < 4; ++j) {
        int ccol = j * 16 + l16 + kw;
        bfr[j] = *(const bf16x8*)&xs[(rr * 66 + ccol) * CIPAD + quad * 8];
      }
      const unsigned short* wp =
          effw + ((((size_t)e * 4 + cc) * 16 + bxc * 8) * 64 + lane) * 8;
      #pragma unroll
      for (int mt = 0; mt < 8; ++mt) {
        bf16x8 af = *(const bf16x8*)(wp + (size_t)mt * 512);
        #pragma unroll
        for (int j = 0; j < 4; ++j)
          acc[mt][j] = __builtin_amdgcn_mfma_f32_16x16x32_bf16(af, bfr[j], acc[mt][j], 0, 0, 0);
      }
    }
    __syncthreads();
  }

  const int ho = hbase + wv;
  if (ho < 62) {
    #pragma unroll
    for (int mt = 0; mt < 8; ++mt) {
      const int co = co_blk + mt * 16 + quad * 4;
      #pragma unroll
      for (int j = 0; j < 4; ++j) {
        const int wo = j * 16 + l16;
        if (wo < 62) {
          float* op = out + (((size_t)(bb * 256 + co) * 62 + ho) * 62 + wo);
          #pragma unroll
          for (int rg = 0; rg < 4; ++rg)
            op[(size_t)rg * 3844] = acc[mt][j][rg];
        }
      }
    }
  }
}

extern "C" void kernel_launch(void* const* d_in, const int* in_sizes, int n_in,
                              void* d_out, int out_size, void* d_ws, size_t ws_size,
                              hipStream_t stream) {
  const float* x  = (const float*)d_in[0];
  const float* Wf = (const float*)d_in[1];
  float* out = (float*)d_out;

  unsigned short* effw = (unsigned short*)d_ws;                  // 576KB used
  const size_t XBF_OFF = 2u * 1024u * 1024u;                     // bytes
  const size_t XBF_BYTES = (size_t)32 * 64 * 4 * 64 * 32 * 2;    // 33.55MB
  unsigned short* xbf = (unsigned short*)((char*)d_ws + XBF_OFF);

  prepack_w_kernel<<<dim3((9 * 4 * 16 * 64 * 8 + 255) / 256), dim3(256), 0, stream>>>(Wf, effw);

  dim3 grid(2, 16, 32);
  if (ws_size >= XBF_OFF + XBF_BYTES) {
    prepack_x_kernel<<<dim3(2097152 / 256), dim3(256), 0, stream>>>(x, xbf);
    xorconv_mfma_pre<<<grid, dim3(256), 0, stream>>>(xbf, effw, out);
  } else {
    xorconv_mfma_fb<<<grid, dim3(256), 0, stream>>>(x, effw, out);
  }
}